// Round 5
// baseline (580.113 us; speedup 1.0000x reference)
//
#include <hip/hip_runtime.h>
#include <stdint.h>

#define T_DIM 1024
#define B_DIM 64
#define I_DIM 512
#define H_DIM 512
#define M_DIM (T_DIM*B_DIM)          // 65536 rows for both GEMMs
#define BH    (B_DIM*H_DIM)          // 32768
#define OUT_OFF ((size_t)M_DIM*H_DIM)  // 33554432 floats, then hiddens (B, 2H)

typedef __bf16 bf16x8 __attribute__((ext_vector_type(8)));
typedef float  f32x4  __attribute__((ext_vector_type(4)));

// ---------- helpers ----------
__device__ __forceinline__ void split1(float x, ushort& h, ushort& l) {
  // x ≈ bf16(h) + bf16(l), RNE both
  uint32_t u  = __builtin_bit_cast(uint32_t, x);
  uint32_t hr = (u + 0x7FFFu + ((u >> 16) & 1u)) >> 16;
  float    hf = __builtin_bit_cast(float, hr << 16);
  float    lo = x - hf;
  uint32_t ul = __builtin_bit_cast(uint32_t, lo);
  uint32_t lr = (ul + 0x7FFFu + ((ul >> 16) & 1u)) >> 16;
  h = (ushort)hr; l = (ushort)lr;
}

#define GLOAD_LDS16(g, l)                                                     \
  __builtin_amdgcn_global_load_lds(                                           \
      (const __attribute__((address_space(1))) void*)(g),                     \
      (__attribute__((address_space(3))) void*)(l), 16, 0, 0)

#define VMCNT(n) asm volatile("s_waitcnt vmcnt(" #n ")" ::: "memory")

// ---------- split f32 -> (hi, lo) bf16 planes, float4 vectorized ----------
__global__ __launch_bounds__(256)
void split4_kernel(const float4* __restrict__ src, ushort4* __restrict__ hi,
                   ushort4* __restrict__ lo, int n4) {
  int i = blockIdx.x * blockDim.x + threadIdx.x;
  int stride = gridDim.x * blockDim.x;
  for (; i < n4; i += stride) {
    float4 v = src[i];
    ushort4 h4, l4;
    split1(v.x, h4.x, l4.x);
    split1(v.y, h4.y, l4.y);
    split1(v.z, h4.z, l4.z);
    split1(v.w, h4.w, l4.w);
    hi[i] = h4;
    lo[i] = l4;
  }
}

// ---------- 8-phase 256x256 GEMM over virtual K=1536 ----------
// C[m,n] = sum_k (Ahi+Alo)[m,k]*(Whi+Wlo)[n,k] + bias[n], 3-term split.
// Virtual K-tile t (0..23): term = t%3 -> (Ahi,Whi)/(Ahi,Wlo)/(Alo,Whi),
// physical k0 = (t/3)*64. BM=BN=256, BK=64, 512 thr = 8 waves (2M x 4N),
// wave output 128x64 (M_rep 8 x N_rep 4). LDS 128 KB: As/Bs[2 buf][2 khalf]
// of [256 rows][32 k] bf16 (16 KB slots), st_16x32 swizzle
// (byte ^= ((byte>>9)&1)<<5) applied on stage-source AND ds_read (rule #21).
// 4 phases per K-tile: (ks, fm-half). Per phase: ds_read (8 or 4) ->
// stage 1 half-tile (2 gload_lds) -> barrier -> 16 MFMA (setprio) -> barrier.
// Counted vmcnt(4) once per tile (never 0 in steady state); stage lead = 6 phases.
__global__ __launch_bounds__(512, 2)
void gemm8_kernel(const ushort* __restrict__ Ahi, const ushort* __restrict__ Alo,
                  const ushort* __restrict__ Whi, const ushort* __restrict__ Wlo,
                  const float*  __restrict__ bias, float* __restrict__ C) {
  __shared__ __align__(16) ushort As[2][2][8192];
  __shared__ __align__(16) ushort Bs[2][2][8192];

  const int tid  = threadIdx.x;
  const int lane = tid & 63;
  const int w    = tid >> 6;          // wave 0..7
  const int wm   = w >> 2;            // 0..1  (M half)
  const int wn   = w & 3;             // 0..3  (N quarter)
  const int wofs = w * 512;           // wave staging base (ushorts) within a slot

  // XCD-aware bijective swizzle: 512 wg, orig%8 -> XCD; chunk of 64 per XCD.
  const int swz = (blockIdx.x & 7) * 64 + (blockIdx.x >> 3);
  const int bm  = swz >> 1;           // 0..255
  const int bn  = swz & 1;            // 0..1  (pairs share A within an XCD)

  // ---- staging source offsets (inverse-swizzled global, linear LDS dest) ----
  uint32_t offA0, offA1, offB0, offB1;
  {
    const int d0 = tid * 16;                 // load 0 dest byte in slot
    const int d1 = 8192 + tid * 16;          // load 1
    const int s0 = d0 ^ (((d0 >> 9) & 1) << 5);
    const int s1 = d1 ^ (((d1 >> 9) & 1) << 5);
    const int r0 = s0 >> 6, c0 = (s0 & 63) >> 1;
    const int r1 = s1 >> 6, c1 = (s1 & 63) >> 1;
    offA0 = (uint32_t)(bm * 256 + r0) * 512 + c0;
    offA1 = (uint32_t)(bm * 256 + r1) * 512 + c1;
    offB0 = (uint32_t)(bn * 256 + r0) * 512 + c0;
    offB1 = (uint32_t)(bn * 256 + r1) * 512 + c1;
  }

  // ---- fragment ds_read offsets (swizzled), elements within a slot ----
  int aoff[8], boff[4];
#pragma unroll
  for (int fm = 0; fm < 8; ++fm) {
    const int row = wm * 128 + fm * 16 + (lane & 15);
    int byte = row * 64 + (lane >> 4) * 16;
    byte ^= ((byte >> 9) & 1) << 5;
    aoff[fm] = byte >> 1;
  }
#pragma unroll
  for (int fn = 0; fn < 4; ++fn) {
    const int row = wn * 64 + fn * 16 + (lane & 15);
    int byte = row * 64 + (lane >> 4) * 16;
    byte ^= ((byte >> 9) & 1) << 5;
    boff[fn] = byte >> 1;
  }

  f32x4 acc[8][4] = {};

#define STAGE_A(src, k0v, bsel, kh)                                   \
  GLOAD_LDS16((src) + offA0 + (k0v), &As[bsel][kh][wofs]);            \
  GLOAD_LDS16((src) + offA1 + (k0v), &As[bsel][kh][4096 + wofs]);
#define STAGE_B(src, k0v, bsel, kh)                                   \
  GLOAD_LDS16((src) + offB0 + (k0v), &Bs[bsel][kh][wofs]);            \
  GLOAD_LDS16((src) + offB1 + (k0v), &Bs[bsel][kh][4096 + wofs]);

  // ---- prologue: stage halves 0..5 (tile0 all, tile1 kh0), wait, barrier ----
  // tile0: term0 -> (Ahi,Whi), k0=0 ; tile1: term1 -> (Ahi,Wlo), k0=0
  STAGE_A(Ahi, 0, 0, 0); STAGE_B(Whi, 0, 0, 0);
  STAGE_A(Ahi, 32, 0, 1); STAGE_B(Whi, 32, 0, 1);
  STAGE_A(Ahi, 0, 1, 0); STAGE_B(Wlo, 0, 1, 0);
  VMCNT(4);
  __builtin_amdgcn_s_barrier();

#define MFMA_ROW(fmi, areg)                                                    \
  acc[fmi][0] = __builtin_amdgcn_mfma_f32_16x16x32_bf16(areg, bf0, acc[fmi][0], 0, 0, 0); \
  acc[fmi][1] = __builtin_amdgcn_mfma_f32_16x16x32_bf16(areg, bf1, acc[fmi][1], 0, 0, 0); \
  acc[fmi][2] = __builtin_amdgcn_mfma_f32_16x16x32_bf16(areg, bf2, acc[fmi][2], 0, 0, 0); \
  acc[fmi][3] = __builtin_amdgcn_mfma_f32_16x16x32_bf16(areg, bf3, acc[fmi][3], 0, 0, 0);

#pragma unroll 1
  for (int t = 0; t < 24; ++t) {
    const int buf = t & 1;
    const int t1 = t + 1, t2 = t + 2;
    const int bs1 = t1 & 1, bs2 = t2 & 1;
    const int c1 = t1 / 3, e1 = t1 - c1 * 3;
    const int c2 = t2 / 3, e2 = t2 - c2 * 3;
    const ushort* A1 = (e1 == 2) ? Alo : Ahi;
    const ushort* B1 = (e1 == 1) ? Wlo : Whi;
    const ushort* A2 = (e2 == 2) ? Alo : Ahi;
    const ushort* B2 = (e2 == 1) ? Wlo : Whi;
    const int k01 = c1 * 64, k02 = c2 * 64;
    const bool s1 = (t1 < 24), s2 = (t2 < 24);

    bf16x8 af0, af1, af2, af3, bf0, bf1, bf2, bf3;

    // ---- phase 0: ks0, fm 0-3 ----
    bf0 = *(const bf16x8*)&Bs[buf][0][boff[0]];
    bf1 = *(const bf16x8*)&Bs[buf][0][boff[1]];
    bf2 = *(const bf16x8*)&Bs[buf][0][boff[2]];
    bf3 = *(const bf16x8*)&Bs[buf][0][boff[3]];
    af0 = *(const bf16x8*)&As[buf][0][aoff[0]];
    af1 = *(const bf16x8*)&As[buf][0][aoff[1]];
    af2 = *(const bf16x8*)&As[buf][0][aoff[2]];
    af3 = *(const bf16x8*)&As[buf][0][aoff[3]];
    if (s1) { STAGE_A(A1, k01 + 32, bs1, 1); }   // half (t+1, A-kh1)
    __builtin_amdgcn_s_barrier();
    __builtin_amdgcn_s_setprio(1);
    MFMA_ROW(0, af0) MFMA_ROW(1, af1) MFMA_ROW(2, af2) MFMA_ROW(3, af3)
    __builtin_amdgcn_s_setprio(0);
    __builtin_amdgcn_s_barrier();

    // ---- phase 1: ks0, fm 4-7 (B regs persist) ----
    af0 = *(const bf16x8*)&As[buf][0][aoff[4]];
    af1 = *(const bf16x8*)&As[buf][0][aoff[5]];
    af2 = *(const bf16x8*)&As[buf][0][aoff[6]];
    af3 = *(const bf16x8*)&As[buf][0][aoff[7]];
    if (s1) { STAGE_B(B1, k01 + 32, bs1, 1); }   // (t+1, B-kh1)
    __builtin_amdgcn_s_barrier();
    __builtin_amdgcn_s_setprio(1);
    MFMA_ROW(4, af0) MFMA_ROW(5, af1) MFMA_ROW(6, af2) MFMA_ROW(7, af3)
    __builtin_amdgcn_s_setprio(0);
    __builtin_amdgcn_s_barrier();

    // ---- phase 2: ks1, fm 0-3 ----
    bf0 = *(const bf16x8*)&Bs[buf][1][boff[0]];
    bf1 = *(const bf16x8*)&Bs[buf][1][boff[1]];
    bf2 = *(const bf16x8*)&Bs[buf][1][boff[2]];
    bf3 = *(const bf16x8*)&Bs[buf][1][boff[3]];
    af0 = *(const bf16x8*)&As[buf][1][aoff[0]];
    af1 = *(const bf16x8*)&As[buf][1][aoff[1]];
    af2 = *(const bf16x8*)&As[buf][1][aoff[2]];
    af3 = *(const bf16x8*)&As[buf][1][aoff[3]];
    if (s2) { STAGE_A(A2, k02, bs2, 0); }        // (t+2, A-kh0)
    __builtin_amdgcn_s_barrier();
    __builtin_amdgcn_s_setprio(1);
    MFMA_ROW(0, af0) MFMA_ROW(1, af1) MFMA_ROW(2, af2) MFMA_ROW(3, af3)
    __builtin_amdgcn_s_setprio(0);
    __builtin_amdgcn_s_barrier();

    // ---- phase 3: ks1, fm 4-7 ----
    af0 = *(const bf16x8*)&As[buf][1][aoff[4]];
    af1 = *(const bf16x8*)&As[buf][1][aoff[5]];
    af2 = *(const bf16x8*)&As[buf][1][aoff[6]];
    af3 = *(const bf16x8*)&As[buf][1][aoff[7]];
    if (s2) { STAGE_B(B2, k02, bs2, 0); }        // (t+2, B-kh0)
    if (t < 22) { VMCNT(4); } else { VMCNT(0); }
    __builtin_amdgcn_s_barrier();
    __builtin_amdgcn_s_setprio(1);
    MFMA_ROW(4, af0) MFMA_ROW(5, af1) MFMA_ROW(6, af2) MFMA_ROW(7, af3)
    __builtin_amdgcn_s_setprio(0);
    __builtin_amdgcn_s_barrier();
  }

  // ---- epilogue: C = acc + bias ; C/D layout: col=lane&15, row=(lane>>4)*4+j ----
  const int sl = lane >> 4, lr = lane & 15;
  const int cm = bm * 256 + wm * 128;
  const int cn = bn * 256 + wn * 64;
#pragma unroll
  for (int fn = 0; fn < 4; ++fn) {
    const int col = cn + fn * 16 + lr;
    const float bv = bias[col];
#pragma unroll
    for (int fm = 0; fm < 8; ++fm) {
      const int rowb = cm + fm * 16 + sl * 4;
#pragma unroll
      for (int j = 0; j < 4; ++j)
        C[(size_t)(rowb + j) * 512 + col] = acc[fm][fn][j] + bv;
    }
  }
#undef STAGE_A
#undef STAGE_B
#undef MFMA_ROW
}

// ---------- recurrence scan: h_t = relu(lin_t + u*h_{t-1}) ----------
// One thread per (b,h). 32-deep double-buffered register prefetch:
// in-flight = 512 waves x 32 x 256 B = 4 MB -> ~6 TB/s Little's-law ceiling.
template <int MODE>
__global__ __launch_bounds__(64)
void scan_kernel(const float* __restrict__ lin, const float* __restrict__ u,
                 ushort* __restrict__ yhi, ushort* __restrict__ ylo,
                 float* __restrict__ yf, float* __restrict__ hT) {
  const int i = blockIdx.x * 64 + threadIdx.x;   // 0..BH-1
  const float uv = u[i & (H_DIM - 1)];
  const float* p = lin + i;
  float hv = 0.f;
  float va[32], vb[32];

#pragma unroll
  for (int j = 0; j < 32; ++j) va[j] = p[(size_t)j * BH];

  for (int t0 = 0; t0 < T_DIM; t0 += 64) {
#pragma unroll
    for (int j = 0; j < 32; ++j) vb[j] = p[(size_t)(t0 + 32 + j) * BH];
#pragma unroll
    for (int j = 0; j < 32; ++j) {
      hv = fmaxf(fmaf(uv, hv, va[j]), 0.f);
      const size_t o = (size_t)(t0 + j) * BH + i;
      if (MODE == 0) {
        ushort hb, lb; split1(hv, hb, lb);
        yhi[o] = hb; ylo[o] = lb;
      } else {
        yf[o] = hv;
      }
    }
    if (t0 + 64 < T_DIM) {
#pragma unroll
      for (int j = 0; j < 32; ++j) va[j] = p[(size_t)(t0 + 64 + j) * BH];
    }
#pragma unroll
    for (int j = 0; j < 32; ++j) {
      hv = fmaxf(fmaf(uv, hv, vb[j]), 0.f);
      const size_t o = (size_t)(t0 + 32 + j) * BH + i;
      if (MODE == 0) {
        ushort hb, lb; split1(hv, hb, lb);
        yhi[o] = hb; ylo[o] = lb;
      } else {
        yf[o] = hv;
      }
    }
  }
  hT[(i >> 9) * (2 * H_DIM) + (i & (H_DIM - 1))] = hv;
}

// ---------- launch ----------
extern "C" void kernel_launch(void* const* d_in, const int* in_sizes, int n_in,
                              void* d_out, int out_size, void* d_ws, size_t ws_size,
                              hipStream_t stream) {
  const float* x  = (const float*)d_in[0];
  const float* W0 = (const float*)d_in[1];
  const float* b0 = (const float*)d_in[2];
  const float* u0 = (const float*)d_in[3];
  const float* W1 = (const float*)d_in[4];
  const float* b1 = (const float*)d_in[5];
  const float* u1 = (const float*)d_in[6];
  float* out = (float*)d_out;

  // workspace layout (bytes):
  //   lin   : f32 [65536 x 512]           = 134217728
  //   phi   : bf16 plane [65536 x 512]    =  67108864   (x_hi, then reused as ys0_hi)
  //   plo   : bf16 plane [65536 x 512]    =  67108864
  //   w0hi/w0lo/w1hi/w1lo : 512x512 bf16  =   524288 each
  char* ws = (char*)d_ws;
  float*  lin  = (float*)ws;
  ushort* phi  = (ushort*)(ws + 134217728ull);
  ushort* plo  = (ushort*)(ws + 201326592ull);
  ushort* w0hi = (ushort*)(ws + 268435456ull);
  ushort* w0lo = w0hi + 262144;
  ushort* w1hi = w0lo + 262144;
  ushort* w1lo = w1hi + 262144;

  // 1) split inputs to bf16 hi/lo planes
  split4_kernel<<<2048, 256, 0, stream>>>((const float4*)x,  (ushort4*)phi,  (ushort4*)plo,  M_DIM*I_DIM/4);
  split4_kernel<<<256,  256, 0, stream>>>((const float4*)W0, (ushort4*)w0hi, (ushort4*)w0lo, H_DIM*I_DIM/4);
  split4_kernel<<<256,  256, 0, stream>>>((const float4*)W1, (ushort4*)w1hi, (ushort4*)w1lo, H_DIM*H_DIM/4);

  // 2) lin0 = x @ W0^T + b0
  gemm8_kernel<<<512, 512, 0, stream>>>(phi, plo, w0hi, w0lo, b0, lin);

  // 3) scan layer 0 -> ys0 split planes (reuse phi/plo) + hT0
  scan_kernel<0><<<BH/64, 64, 0, stream>>>(lin, u0, phi, plo, nullptr, out + OUT_OFF);

  // 4) lin1 = ys0 @ W1^T + b1
  gemm8_kernel<<<512, 512, 0, stream>>>(phi, plo, w1hi, w1lo, b1, lin);

  // 5) scan layer 1 -> out (T,B,H) + hT1
  scan_kernel<1><<<BH/64, 64, 0, stream>>>(lin, u1, nullptr, nullptr, out, out + OUT_OFF + H_DIM);
}